// Round 4
// baseline (24730.856 us; speedup 1.0000x reference)
//
#include <hip/hip_runtime.h>
#include <hip/hip_cooperative_groups.h>
#include <cstdint>
#include <cstddef>
#include <type_traits>

namespace cg = cooperative_groups;

// LSTM decoder: SEQ=256 steps, BATCH=256, HID=1024, OUT=512. f32 in/out.
// Folded recurrence (Wc2 = W_ih @ W_out): each step is ONE GEMM
//   gates = [h | c] @ [W_hh | Wc2]^T  (M=256, N=4096, K=2048, bf16 MFMA)
// Round-4 structure: ONE persistent cooperative kernel runs all 256 steps.
//   - 256 WGs x 512 thr (1/CU). Weights live in REGISTERS (32 bf16x8 frags
//     = 128 VGPR/lane), loaded once. Only A = [h|c] (1 MB) moves per step.
//   - A staged global->LDS in 4 dbuf 64KB chunks (global_load_lds w=16,
//     source-side XOR swizzle). Waves: 2(n) x 4(k-split); LDS reduction of
//     k-partials; LSTM epilogue with cell state in VGPRs. grid.sync()/step.
// Scratch lives in the `outs` third of d_out; d_ws unused.

#define SEQ    256
#define BATCH  256
#define HID    1024
#define OUTD   512
#define KDIM   2048
#define GATES  4096

typedef __bf16 bf16x8 __attribute__((ext_vector_type(8)));
typedef float  f32x4  __attribute__((ext_vector_type(4)));

__device__ __forceinline__ unsigned short f2bf(float x) {
  unsigned u = __float_as_uint(x);
  u = (u + 0x7FFFu + ((u >> 16) & 1u)) >> 16;   // RNE
  return (unsigned short)u;
}

__device__ __forceinline__ f32x4 mfma16(bf16x8 a, bf16x8 b, f32x4 c) {
  return __builtin_amdgcn_mfma_f32_16x16x32_bf16(a, b, c, 0, 0, 0);
}

__device__ __forceinline__ bf16x8 ld_frag_bf(const unsigned short* p) {
  uint4 u = *reinterpret_cast<const uint4*>(p);
  return __builtin_bit_cast(bf16x8, u);
}

#define GLOAD_LDS16(gp, lp)                                                   \
  __builtin_amdgcn_global_load_lds(                                           \
      (const __attribute__((address_space(1))) unsigned int*)(gp),            \
      (__attribute__((address_space(3))) unsigned int*)(lp), 16, 0, 0)

// ---------------- prep kernels ----------------

__global__ void k_cast_whh(const float* __restrict__ whh, unsigned short* __restrict__ wg2) {
  int i4 = blockIdx.x * blockDim.x + threadIdx.x;
  if (i4 >= (GATES * HID) / 4) return;
  int idx = i4 * 4;
  int n = idx >> 10, k = idx & 1023;
  const float4 v = *reinterpret_cast<const float4*>(whh + idx);
  ushort4 o; o.x = f2bf(v.x); o.y = f2bf(v.y); o.z = f2bf(v.z); o.w = f2bf(v.w);
  *reinterpret_cast<ushort4*>(wg2 + (size_t)n * KDIM + k) = o;
}

__global__ void k_cast_wout(const float* __restrict__ wout,
                            unsigned short* __restrict__ wott) {
  int idx = blockIdx.x * blockDim.x + threadIdx.x;
  if (idx >= OUTD * HID) return;
  int j = idx >> 10, k = idx & 1023;
  wott[(size_t)k * OUTD + j] = f2bf(wout[idx]);
}

// A0 = [bf16(c_vector) | 0]
__global__ void k_init(const float* __restrict__ cvec, unsigned short* __restrict__ a0) {
  int idx = blockIdx.x * blockDim.x + threadIdx.x;
  if (idx >= BATCH * KDIM) return;
  int b = idx >> 11, k = idx & 2047;
  a0[idx] = (k < HID) ? f2bf(cvec[(size_t)b * HID + k]) : (unsigned short)0;
}

// bias0[n] = b_ih+b_hh ; bias2[n] = bias0[n] + dot(W_ih[n,:], b_out)
__global__ void k_bias(const float* __restrict__ wih, const float* __restrict__ b_ih,
                       const float* __restrict__ b_hh, const float* __restrict__ b_out,
                       float* __restrict__ bias0, float* __restrict__ bias2) {
  int wave = threadIdx.x >> 6, l = threadIdx.x & 63;
  int n = blockIdx.x * 4 + wave;
  float s = 0.f;
  for (int j = l; j < OUTD; j += 64) s += wih[(size_t)n * OUTD + j] * b_out[j];
  for (int off = 32; off; off >>= 1) s += __shfl_down(s, off);
  if (l == 0) {
    float b0 = b_ih[n] + b_hh[n];
    bias0[n] = b0;
    bias2[n] = b0 + s;
  }
}

// ---------------- generic bf16-MFMA GEMM (unchanged, passing) ----------
template <typename AT>
__device__ __forceinline__ bf16x8 ld_frag(const AT* p) {
  if constexpr (std::is_same_v<AT, float>) {
    const float4 f0 = *reinterpret_cast<const float4*>(p);
    const float4 f1 = *reinterpret_cast<const float4*>(p + 4);
    uint4 v;
    v.x = (unsigned)f2bf(f0.x) | ((unsigned)f2bf(f0.y) << 16);
    v.y = (unsigned)f2bf(f0.z) | ((unsigned)f2bf(f0.w) << 16);
    v.z = (unsigned)f2bf(f1.x) | ((unsigned)f2bf(f1.y) << 16);
    v.w = (unsigned)f2bf(f1.z) | ((unsigned)f2bf(f1.w) << 16);
    return __builtin_bit_cast(bf16x8, v);
  } else {
    return ld_frag_bf(p);
  }
}

template <typename AT, typename BT, typename DT>
__global__ __launch_bounds__(256)
void k_gemm(const AT* __restrict__ A, int lda,
            const BT* __restrict__ Bn, int ldb,
            DT* __restrict__ D, int ldd,
            const float* __restrict__ bias, int K) {
  __shared__ char lds[64 * 1024];
  const int tid = threadIdx.x;
  const int w = tid >> 6, l = tid & 63;
  const int n0 = blockIdx.x * 64;
  const int m0 = blockIdx.y * 64 + w * 16;
  const int lr = l & 15, lg = l >> 4;

  f32x4 acc[4] = {};
  for (int kc = 0; kc < K; kc += 512) {
    __syncthreads();
    for (int it = 0; it < 16; ++it) {
      int idx = tid + it * 256;
      int col = idx >> 6, k16 = idx & 63;
      uint4 v;
      if constexpr (std::is_same_v<BT, float>) {
        const float* src = Bn + (size_t)(n0 + col) * ldb + kc + k16 * 8;
        const float4 f0 = *reinterpret_cast<const float4*>(src);
        const float4 f1 = *reinterpret_cast<const float4*>(src + 4);
        v.x = (unsigned)f2bf(f0.x) | ((unsigned)f2bf(f0.y) << 16);
        v.y = (unsigned)f2bf(f0.z) | ((unsigned)f2bf(f0.w) << 16);
        v.z = (unsigned)f2bf(f1.x) | ((unsigned)f2bf(f1.y) << 16);
        v.w = (unsigned)f2bf(f1.z) | ((unsigned)f2bf(f1.w) << 16);
      } else {
        v = *reinterpret_cast<const uint4*>(Bn + (size_t)(n0 + col) * ldb + kc + k16 * 8);
      }
      int db = col * 1024 + ((k16 * 16) ^ ((col & 7) << 4));
      *reinterpret_cast<uint4*>(lds + db) = v;
    }
    __syncthreads();
    const AT* Arow = A + (size_t)(m0 + lr) * lda + kc + lg * 8;
#pragma unroll
    for (int ks = 0; ks < 16; ++ks) {
      bf16x8 af = ld_frag(Arow + ks * 32);
      int kb = ks * 64 + lg * 16;
#pragma unroll
      for (int f = 0; f < 4; ++f) {
        int col = f * 16 + lr;
        uint4 u = *reinterpret_cast<const uint4*>(lds + col * 1024 + (kb ^ ((col & 7) << 4)));
        acc[f] = mfma16(af, __builtin_bit_cast(bf16x8, u), acc[f]);
      }
    }
  }
#pragma unroll
  for (int f = 0; f < 4; ++f) {
    int cg = n0 + f * 16 + lr;
    float bv = bias ? bias[cg] : 0.f;
#pragma unroll
    for (int j = 0; j < 4; ++j) {
      int r = m0 + lg * 4 + j;
      float val = acc[f][j] + bv;
      if constexpr (std::is_same_v<DT, unsigned short>) D[(size_t)r * ldd + cg] = f2bf(val);
      else                                              D[(size_t)r * ldd + cg] = val;
    }
  }
}

// ---------------- persistent LSTM recurrence ----------------
// WG (mg,ng): mg = wg>>6 (64 batch rows), ng = wg&63 (16 hidden cols = 64
// gate rows). wg%8 == ng%8 -> the 4 m-siblings of an n-group share an XCD.
// Waves: wn = wave>>2 (32 gate-cols), wk = wave&3 (k-split). Each wave:
// 64m x 32n, k in {c*512 + wk*128 + [0,128) : c=0..3}. B-frags in regs.
__global__ __launch_bounds__(512, 2)
void k_lstm(unsigned short* __restrict__ Ab0,
            unsigned short* __restrict__ Ab1,
            const unsigned short* __restrict__ Wg2,
            const float* __restrict__ bias0,
            const float* __restrict__ bias2,
            const float* __restrict__ cvec,
            float* __restrict__ hs,
            float* __restrict__ cs) {
  __shared__ char lds[131072];
  cg::grid_group grid = cg::this_grid();
  const int tid = threadIdx.x;
  const int wave = tid >> 6, l = tid & 63;
  const int wn = wave >> 2, wk = wave & 3;
  const int mg = blockIdx.x >> 6, ng = blockIdx.x & 63;
  const int lr = l & 15, lg = l >> 4;

  // ---- one-time: weight fragments into registers (32 frags = 128 VGPR) ----
  bf16x8 B[4][4][2];   // [chunk c][kk][in]
#pragma unroll
  for (int c = 0; c < 4; ++c)
#pragma unroll
    for (int kk = 0; kk < 4; ++kk)
#pragma unroll
      for (int in = 0; in < 2; ++in) {
        int col = wn * 32 + in * 16 + lr;                  // WG gate-col 0..63
        int grow = (col >> 4) * HID + ng * 16 + (col & 15);
        int kb = c * 512 + wk * 128 + kk * 32 + lg * 8;
        B[c][kk][in] = ld_frag_bf(Wg2 + (size_t)grow * KDIM + kb);
      }

  // ---- one-time: per-thread cell state + bias registers ----
  const int m = tid >> 3;            // 0..63 (batch row within WG)
  const int hcp = tid & 7;           // cell pair
  const int b_row = mg * 64 + m;
  float creg[2], b2r[2][4];
#pragma unroll
  for (int e = 0; e < 2; ++e) {
    int hid = ng * 16 + hcp * 2 + e;
    creg[e] = cvec[(size_t)b_row * HID + hid];
#pragma unroll
    for (int g = 0; g < 4; ++g) b2r[e][g] = bias2[g * HID + hid];
  }

  for (int t = 0; t < SEQ; ++t) {
    const unsigned short* Acur = (t & 1) ? Ab1 : Ab0;
    unsigned short* Anxt = (t & 1) ? Ab0 : Ab1;

    // stage chunk c of A (64 rows x 512 k bf16 = 64KB) into LDS half
    auto STAGE = [&](int half, int c) {
      const unsigned short* base = Acur + (size_t)(mg * 64) * KDIM + c * 512;
#pragma unroll
      for (int i = 0; i < 8; ++i) {
        int row = i * 8 + wave;                       // wave-uniform
        const unsigned short* g =
            base + (size_t)row * KDIM + ((l ^ (row & 7)) * 8);  // src swizzle
        GLOAD_LDS16(g, lds + half * 65536 + row * 1024);
      }
    };

    f32x4 acc[4][2] = {};
    STAGE(0, 0);
    __syncthreads();                                  // vmcnt(0) drain + bar
#pragma unroll
    for (int c = 0; c < 4; ++c) {
      if (c < 3) STAGE((c + 1) & 1, c + 1);
      const char* half = lds + (c & 1) * 65536;
#pragma unroll
      for (int kk = 0; kk < 4; ++kk) {
        bf16x8 a[4];
#pragma unroll
        for (int im = 0; im < 4; ++im) {
          int row = im * 16 + lr;
          int k16 = wk * 16 + kk * 4 + lg;            // 16B slot in chunk
          a[im] = *reinterpret_cast<const bf16x8*>(
              half + row * 1024 + ((k16 ^ (row & 7)) << 4));
        }
#pragma unroll
        for (int im = 0; im < 4; ++im)
#pragma unroll
          for (int in = 0; in < 2; ++in)
            acc[im][in] = mfma16(a[im], B[c][kk][in], acc[im][in]);
      }
      __syncthreads();                                // drains c+1 stage too
    }

    // ---- dump k-partials: [wave][frag][lane] (conflict-free writes) ----
#pragma unroll
    for (int im = 0; im < 4; ++im)
#pragma unroll
      for (int in = 0; in < 2; ++in)
        *reinterpret_cast<f32x4*>(lds + wave * 8192 + (im * 2 + in) * 1024 + l * 16) =
            acc[im][in];
    __syncthreads();

    // ---- epilogue: 2 cells/thread, 4-way k-reduction from LDS ----
#pragma unroll
    for (int e = 0; e < 2; ++e) {
      int hc = hcp * 2 + e;
      int hid = ng * 16 + hc;
      float pre[4];
#pragma unroll
      for (int g = 0; g < 4; ++g) {
        int n = g * 16 + hc;                          // WG gate-col
        int wn_r = n >> 5, nn = n & 31;
        int frag = ((m >> 4) << 1) | (nn >> 4);
        int lane_r = ((m & 15) >> 2) * 16 + (nn & 15);
        int j = m & 3;
        float s = 0.f;
#pragma unroll
        for (int wkk = 0; wkk < 4; ++wkk)
          s += *reinterpret_cast<const float*>(
              lds + (wn_r * 4 + wkk) * 8192 + frag * 1024 + lane_r * 16 + j * 4);
        pre[g] = s + ((t == 0) ? bias0[g * HID + hid] : b2r[e][g]);
      }
      float si = 1.f / (1.f + __expf(-pre[0]));
      float sf = 1.f / (1.f + __expf(-pre[1]));
      float tg = tanhf(pre[2]);
      float so = 1.f / (1.f + __expf(-pre[3]));
      float cn = sf * creg[e] + si * tg;
      float hn = so * tanhf(cn);
      creg[e] = cn;
      Anxt[(size_t)b_row * KDIM + hid] = f2bf(hn);
      Anxt[(size_t)b_row * KDIM + HID + hid] = f2bf(cn);
      size_t o = (size_t)b_row * (SEQ * HID) + (size_t)t * HID + hid;
      hs[o] = hn;
      cs[o] = cn;
    }

    __threadfence();                                  // cross-XCD visibility
    grid.sync();
  }
}

// ---------------- launch ----------------
extern "C" void kernel_launch(void* const* d_in, const int* in_sizes, int n_in,
                              void* d_out, int out_size, void* d_ws, size_t ws_size,
                              hipStream_t stream) {
  const float* c_vec = (const float*)d_in[0];
  const float* W_ih  = (const float*)d_in[1];
  const float* W_hh  = (const float*)d_in[2];
  const float* b_ih  = (const float*)d_in[3];
  const float* b_hh  = (const float*)d_in[4];
  const float* W_out = (const float*)d_in[5];
  const float* b_out = (const float*)d_in[6];

  float* out = (float*)d_out;
  float* hs = out;
  float* cs = out + (size_t)BATCH * SEQ * HID;
  float* os = out + (size_t)2 * BATCH * SEQ * HID;

  // Scratch in the `outs` region (128 MB; final GEMM reads nothing from it).
  char* sc = (char*)os;
  unsigned short* Wg2   = (unsigned short*)(sc);                 // 16 MB
  unsigned short* WoTT  = (unsigned short*)(sc + (16u << 20));   // 1 MB
  unsigned short* A0    = (unsigned short*)(sc + (17u << 20));   // 1 MB
  unsigned short* A1    = (unsigned short*)(sc + (18u << 20));   // 1 MB
  float*          bias0 = (float*)(sc + (19u << 20));
  float*          bias2 = (float*)(sc + (19u << 20) + 16384);

  k_cast_whh<<<dim3(GATES * HID / 4 / 256), dim3(256), 0, stream>>>(W_hh, Wg2);
  k_cast_wout<<<dim3(OUTD * HID / 256), dim3(256), 0, stream>>>(W_out, WoTT);
  k_init<<<dim3(BATCH * KDIM / 256), dim3(256), 0, stream>>>(c_vec, A0);
  k_bias<<<dim3(GATES / 4), dim3(256), 0, stream>>>(W_ih, b_ih, b_hh, b_out, bias0, bias2);
  // Wc2 = W_ih @ W_out -> Wg2[:, 1024:2048]
  k_gemm<float, unsigned short, unsigned short>
      <<<dim3(HID / 64, GATES / 64), dim3(256), 0, stream>>>(
      W_ih, OUTD, WoTT, OUTD, Wg2 + HID, KDIM, (const float*)nullptr, OUTD);

  // persistent recurrence: all 256 steps in one cooperative kernel
  {
    void* args[] = {(void*)&A0, (void*)&A1, (void*)&Wg2, (void*)&bias0,
                    (void*)&bias2, (void*)&c_vec, (void*)&hs, (void*)&cs};
    hipLaunchCooperativeKernel((const void*)k_lstm, dim3(256), dim3(512),
                               args, 0, stream);
  }

  // outs = cs @ W_out^T + b_out  (M = 65536, N = 512, K = 1024)
  k_gemm<float, float, float>
      <<<dim3(OUTD / 64, BATCH * SEQ / 64), dim3(256), 0, stream>>>(
      cs, HID, W_out, HID, os, OUTD, b_out, HID);
}

// Round 5
// 4807.808 us; speedup vs baseline: 5.1439x; 5.1439x over previous
//
#include <hip/hip_runtime.h>
#include <cstdint>
#include <cstddef>
#include <type_traits>

// LSTM decoder: SEQ=256 steps, BATCH=256, HID=1024, OUT=512. f32 in/out.
// Folded recurrence (Wc2 = W_ih @ W_out): each step is ONE GEMM
//   gates = [h | c] @ [W_hh | Wc2]^T  (M=256, N=4096, K=2048, bf16 MFMA)
// Round-5 structure: back to ONE KERNEL PER STEP (kernel boundary = cheap
// CP-driven coherence; round-4's in-kernel grid.sync + device fence cost
// ~90us/step). Step kernel: 256 WGs x 512 thr (8 waves = 2/SIMD),
// weights -> registers once per launch, A global_load_lds double-buffered,
// k-split 4 with LDS partial reduce, fused LSTM epilogue.
// Scratch lives in the `outs` third of d_out; d_ws unused.

#define SEQ    256
#define BATCH  256
#define HID    1024
#define OUTD   512
#define KDIM   2048
#define GATES  4096

typedef __bf16 bf16x8 __attribute__((ext_vector_type(8)));
typedef float  f32x4  __attribute__((ext_vector_type(4)));

__device__ __forceinline__ unsigned short f2bf(float x) {
  unsigned u = __float_as_uint(x);
  u = (u + 0x7FFFu + ((u >> 16) & 1u)) >> 16;   // RNE
  return (unsigned short)u;
}

__device__ __forceinline__ f32x4 mfma16(bf16x8 a, bf16x8 b, f32x4 c) {
  return __builtin_amdgcn_mfma_f32_16x16x32_bf16(a, b, c, 0, 0, 0);
}

__device__ __forceinline__ bf16x8 ld_frag_bf(const unsigned short* p) {
  uint4 u = *reinterpret_cast<const uint4*>(p);
  return __builtin_bit_cast(bf16x8, u);
}

#define GLOAD_LDS16(gp, lp)                                                   \
  __builtin_amdgcn_global_load_lds(                                           \
      (const __attribute__((address_space(1))) unsigned int*)(gp),            \
      (__attribute__((address_space(3))) unsigned int*)(lp), 16, 0, 0)

// ---------------- prep kernels ----------------

__global__ void k_cast_whh(const float* __restrict__ whh, unsigned short* __restrict__ wg2) {
  int i4 = blockIdx.x * blockDim.x + threadIdx.x;
  if (i4 >= (GATES * HID) / 4) return;
  int idx = i4 * 4;
  int n = idx >> 10, k = idx & 1023;
  const float4 v = *reinterpret_cast<const float4*>(whh + idx);
  ushort4 o; o.x = f2bf(v.x); o.y = f2bf(v.y); o.z = f2bf(v.z); o.w = f2bf(v.w);
  *reinterpret_cast<ushort4*>(wg2 + (size_t)n * KDIM + k) = o;
}

__global__ void k_cast_wout(const float* __restrict__ wout,
                            unsigned short* __restrict__ wott) {
  int idx = blockIdx.x * blockDim.x + threadIdx.x;
  if (idx >= OUTD * HID) return;
  int j = idx >> 10, k = idx & 1023;
  wott[(size_t)k * OUTD + j] = f2bf(wout[idx]);
}

// A0 = [bf16(c_vector) | 0]; cbuf = c_vector (f32 master cell state)
__global__ void k_init(const float* __restrict__ cvec,
                       unsigned short* __restrict__ a0, float* __restrict__ cbuf) {
  int idx = blockIdx.x * blockDim.x + threadIdx.x;
  if (idx >= BATCH * KDIM) return;
  int b = idx >> 11, k = idx & 2047;
  if (k < HID) {
    float v = cvec[(size_t)b * HID + k];
    a0[idx] = f2bf(v);
    cbuf[(size_t)b * HID + k] = v;
  } else {
    a0[idx] = 0;
  }
}

// bias0[n] = b_ih+b_hh ; bias2[n] = bias0[n] + dot(W_ih[n,:], b_out)
__global__ void k_bias(const float* __restrict__ wih, const float* __restrict__ b_ih,
                       const float* __restrict__ b_hh, const float* __restrict__ b_out,
                       float* __restrict__ bias0, float* __restrict__ bias2) {
  int wave = threadIdx.x >> 6, l = threadIdx.x & 63;
  int n = blockIdx.x * 4 + wave;
  float s = 0.f;
  for (int j = l; j < OUTD; j += 64) s += wih[(size_t)n * OUTD + j] * b_out[j];
  for (int off = 32; off; off >>= 1) s += __shfl_down(s, off);
  if (l == 0) {
    float b0 = b_ih[n] + b_hh[n];
    bias0[n] = b0;
    bias2[n] = b0 + s;
  }
}

// ---------------- generic bf16-MFMA GEMM (unchanged, passing) ----------
template <typename AT>
__device__ __forceinline__ bf16x8 ld_frag(const AT* p) {
  if constexpr (std::is_same_v<AT, float>) {
    const float4 f0 = *reinterpret_cast<const float4*>(p);
    const float4 f1 = *reinterpret_cast<const float4*>(p + 4);
    uint4 v;
    v.x = (unsigned)f2bf(f0.x) | ((unsigned)f2bf(f0.y) << 16);
    v.y = (unsigned)f2bf(f0.z) | ((unsigned)f2bf(f0.w) << 16);
    v.z = (unsigned)f2bf(f1.x) | ((unsigned)f2bf(f1.y) << 16);
    v.w = (unsigned)f2bf(f1.z) | ((unsigned)f2bf(f1.w) << 16);
    return __builtin_bit_cast(bf16x8, v);
  } else {
    return ld_frag_bf(p);
  }
}

template <typename AT, typename BT, typename DT>
__global__ __launch_bounds__(256)
void k_gemm(const AT* __restrict__ A, int lda,
            const BT* __restrict__ Bn, int ldb,
            DT* __restrict__ D, int ldd,
            const float* __restrict__ bias, int K) {
  __shared__ char lds[64 * 1024];
  const int tid = threadIdx.x;
  const int w = tid >> 6, l = tid & 63;
  const int n0 = blockIdx.x * 64;
  const int m0 = blockIdx.y * 64 + w * 16;
  const int lr = l & 15, lg = l >> 4;

  f32x4 acc[4] = {};
  for (int kc = 0; kc < K; kc += 512) {
    __syncthreads();
    for (int it = 0; it < 16; ++it) {
      int idx = tid + it * 256;
      int col = idx >> 6, k16 = idx & 63;
      uint4 v;
      if constexpr (std::is_same_v<BT, float>) {
        const float* src = Bn + (size_t)(n0 + col) * ldb + kc + k16 * 8;
        const float4 f0 = *reinterpret_cast<const float4*>(src);
        const float4 f1 = *reinterpret_cast<const float4*>(src + 4);
        v.x = (unsigned)f2bf(f0.x) | ((unsigned)f2bf(f0.y) << 16);
        v.y = (unsigned)f2bf(f0.z) | ((unsigned)f2bf(f0.w) << 16);
        v.z = (unsigned)f2bf(f1.x) | ((unsigned)f2bf(f1.y) << 16);
        v.w = (unsigned)f2bf(f1.z) | ((unsigned)f2bf(f1.w) << 16);
      } else {
        v = *reinterpret_cast<const uint4*>(Bn + (size_t)(n0 + col) * ldb + kc + k16 * 8);
      }
      int db = col * 1024 + ((k16 * 16) ^ ((col & 7) << 4));
      *reinterpret_cast<uint4*>(lds + db) = v;
    }
    __syncthreads();
    const AT* Arow = A + (size_t)(m0 + lr) * lda + kc + lg * 8;
#pragma unroll
    for (int ks = 0; ks < 16; ++ks) {
      bf16x8 af = ld_frag(Arow + ks * 32);
      int kb = ks * 64 + lg * 16;
#pragma unroll
      for (int f = 0; f < 4; ++f) {
        int col = f * 16 + lr;
        uint4 u = *reinterpret_cast<const uint4*>(lds + col * 1024 + (kb ^ ((col & 7) << 4)));
        acc[f] = mfma16(af, __builtin_bit_cast(bf16x8, u), acc[f]);
      }
    }
  }
#pragma unroll
  for (int f = 0; f < 4; ++f) {
    int cg = n0 + f * 16 + lr;
    float bv = bias ? bias[cg] : 0.f;
#pragma unroll
    for (int j = 0; j < 4; ++j) {
      int r = m0 + lg * 4 + j;
      float val = acc[f][j] + bv;
      if constexpr (std::is_same_v<DT, unsigned short>) D[(size_t)r * ldd + cg] = f2bf(val);
      else                                              D[(size_t)r * ldd + cg] = val;
    }
  }
}

// ---------------- per-step fused LSTM kernel ----------------
// WG (mg,ng): mg = bid>>6 (64 batch rows), ng = bid&63 (16 hid cols = 64 gate
// rows). m-siblings of an ng are bids {ng, 64+ng, 128+ng, 192+ng} == same
// mod-8 -> same XCD (heuristic L2 sharing of the 256KB B-slice).
// Waves: wn = wave>>2 (32 gate-cols), wk = wave&3 (k-split 4). B-frags in
// registers (32 x bf16x8, loaded once per launch). A (64 rows x 2048) staged
// global->LDS in 4 double-buffered 64KB chunks. LDS partial-dump k-reduce,
// then LSTM epilogue (f32 cell master in cbuf).
__global__ __launch_bounds__(512, 2)
void k_step2(const unsigned short* __restrict__ Acur,
             unsigned short* __restrict__ Anxt,
             float* __restrict__ cbuf,
             const unsigned short* __restrict__ Wg2,
             const float* __restrict__ bias,
             float* __restrict__ hs,
             float* __restrict__ cs,
             int t) {
  __shared__ char lds[131072];
  const int tid = threadIdx.x;
  const int wave = tid >> 6, l = tid & 63;
  const int wn = wave >> 2, wk = wave & 3;
  const int mg = blockIdx.x >> 6, ng = blockIdx.x & 63;
  const int lr = l & 15, lg = l >> 4;

  // ---- weight fragments -> registers (32 frags = 128 VGPR/AGPR) ----
  bf16x8 B[4][4][2];   // [chunk c][kk][in]
#pragma unroll
  for (int c = 0; c < 4; ++c)
#pragma unroll
    for (int kk = 0; kk < 4; ++kk)
#pragma unroll
      for (int in = 0; in < 2; ++in) {
        int col = wn * 32 + in * 16 + lr;                  // WG gate-col 0..63
        int grow = (col >> 4) * HID + ng * 16 + (col & 15);
        int kb = c * 512 + wk * 128 + kk * 32 + lg * 8;
        B[c][kk][in] = ld_frag_bf(Wg2 + (size_t)grow * KDIM + kb);
      }

  // stage chunk c of A (64 rows x 512 k bf16 = 64KB) into LDS half.
  // bank swizzle f(row) = (row ^ (row>>3)) & 7 : spreads 16 frag-rows over
  // 8 banks at 2-way (free), vs (row&7) which left lr/lr+8 colliding.
  auto STAGE = [&](int half, int c) {
    const unsigned short* base = Acur + (size_t)(mg * 64) * KDIM + c * 512;
#pragma unroll
    for (int i = 0; i < 8; ++i) {
      int row = i * 8 + wave;                              // wave-uniform
      int f = (row ^ (row >> 3)) & 7;
      const unsigned short* g = base + (size_t)row * KDIM + ((l ^ f) * 8);
      GLOAD_LDS16(g, lds + half * 65536 + row * 1024);
    }
  };

  f32x4 acc[4][2] = {};
  STAGE(0, 0);
  __syncthreads();                                         // drains vmcnt
#pragma unroll
  for (int c = 0; c < 4; ++c) {
    if (c < 3) STAGE((c + 1) & 1, c + 1);
    const char* half = lds + (c & 1) * 65536;
#pragma unroll
    for (int kk = 0; kk < 4; ++kk) {
      bf16x8 a[4];
#pragma unroll
      for (int im = 0; im < 4; ++im) {
        int row = im * 16 + lr;
        int f = (row ^ (row >> 3)) & 7;
        int k16 = wk * 16 + kk * 4 + lg;                   // 16B slot index
        a[im] = *reinterpret_cast<const bf16x8*>(
            half + row * 1024 + ((k16 ^ f) << 4));
      }
#pragma unroll
      for (int im = 0; im < 4; ++im)
#pragma unroll
        for (int in = 0; in < 2; ++in)
          acc[im][in] = mfma16(a[im], B[c][kk][in], acc[im][in]);
    }
    __syncthreads();                                       // also drains stage
  }

  // ---- dump k-partials: [wave][frag][lane] (minimal-conflict writes) ----
#pragma unroll
  for (int im = 0; im < 4; ++im)
#pragma unroll
    for (int in = 0; in < 2; ++in)
      *reinterpret_cast<f32x4*>(lds + wave * 8192 + (im * 2 + in) * 1024 + l * 16) =
          acc[im][in];
  __syncthreads();

  // ---- epilogue: 2 consecutive cells/thread, 4-way k-reduce from LDS ----
  const int m = tid >> 3;                                  // batch row in WG
  const int hcp = tid & 7;
  const int b_row = mg * 64 + m;
  const int hid0 = ng * 16 + hcp * 2;
  const float2 cold = *reinterpret_cast<const float2*>(cbuf + (size_t)b_row * HID + hid0);
  float cn2[2], hn2[2];
#pragma unroll
  for (int e = 0; e < 2; ++e) {
    int hc = hcp * 2 + e;
    float pre[4];
#pragma unroll
    for (int g = 0; g < 4; ++g) {
      int n = g * 16 + hc;                                 // WG gate-col
      int wn_r = n >> 5, nn = n & 31;
      int frag = ((m >> 4) << 1) | (nn >> 4);
      int lane_r = ((m & 15) >> 2) * 16 + (nn & 15);
      int j = m & 3;
      float s = 0.f;
#pragma unroll
      for (int wkk = 0; wkk < 4; ++wkk)
        s += *reinterpret_cast<const float*>(
            lds + (wn_r * 4 + wkk) * 8192 + frag * 1024 + lane_r * 16 + j * 4);
      pre[g] = s + bias[g * HID + hid0 + e];
    }
    float si = 1.f / (1.f + __expf(-pre[0]));
    float sf = 1.f / (1.f + __expf(-pre[1]));
    float tg = tanhf(pre[2]);
    float so = 1.f / (1.f + __expf(-pre[3]));
    float co = (e == 0) ? cold.x : cold.y;
    float cn = sf * co + si * tg;
    float hn = so * tanhf(cn);
    cn2[e] = cn;
    hn2[e] = hn;
  }
  *reinterpret_cast<float2*>(cbuf + (size_t)b_row * HID + hid0) = make_float2(cn2[0], cn2[1]);
  unsigned hpack = (unsigned)f2bf(hn2[0]) | ((unsigned)f2bf(hn2[1]) << 16);
  unsigned cpack = (unsigned)f2bf(cn2[0]) | ((unsigned)f2bf(cn2[1]) << 16);
  *reinterpret_cast<unsigned*>(Anxt + (size_t)b_row * KDIM + hid0) = hpack;
  *reinterpret_cast<unsigned*>(Anxt + (size_t)b_row * KDIM + HID + hid0) = cpack;
  size_t o = (size_t)b_row * (SEQ * HID) + (size_t)t * HID + hid0;
  *reinterpret_cast<float2*>(hs + o) = make_float2(hn2[0], hn2[1]);
  *reinterpret_cast<float2*>(cs + o) = make_float2(cn2[0], cn2[1]);
}

// ---------------- launch ----------------
extern "C" void kernel_launch(void* const* d_in, const int* in_sizes, int n_in,
                              void* d_out, int out_size, void* d_ws, size_t ws_size,
                              hipStream_t stream) {
  const float* c_vec = (const float*)d_in[0];
  const float* W_ih  = (const float*)d_in[1];
  const float* W_hh  = (const float*)d_in[2];
  const float* b_ih  = (const float*)d_in[3];
  const float* b_hh  = (const float*)d_in[4];
  const float* W_out = (const float*)d_in[5];
  const float* b_out = (const float*)d_in[6];

  float* out = (float*)d_out;
  float* hs = out;
  float* cs = out + (size_t)BATCH * SEQ * HID;
  float* os = out + (size_t)2 * BATCH * SEQ * HID;

  // Scratch in the `outs` region (128 MB; final GEMM reads nothing from it).
  char* sc = (char*)os;
  unsigned short* Wg2   = (unsigned short*)(sc);                 // 16 MB
  unsigned short* WoTT  = (unsigned short*)(sc + (16u << 20));   // 1 MB
  unsigned short* A0    = (unsigned short*)(sc + (17u << 20));   // 1 MB
  unsigned short* A1    = (unsigned short*)(sc + (18u << 20));   // 1 MB
  float*          cbuf  = (float*)(sc + (19u << 20));            // 1 MB
  float*          bias0 = (float*)(sc + (20u << 20));
  float*          bias2 = (float*)(sc + (20u << 20) + 16384);

  k_cast_whh<<<dim3(GATES * HID / 4 / 256), dim3(256), 0, stream>>>(W_hh, Wg2);
  k_cast_wout<<<dim3(OUTD * HID / 256), dim3(256), 0, stream>>>(W_out, WoTT);
  k_init<<<dim3(BATCH * KDIM / 256), dim3(256), 0, stream>>>(c_vec, A0, cbuf);
  k_bias<<<dim3(GATES / 4), dim3(256), 0, stream>>>(W_ih, b_ih, b_hh, b_out, bias0, bias2);
  // Wc2 = W_ih @ W_out -> Wg2[:, 1024:2048]
  k_gemm<float, unsigned short, unsigned short>
      <<<dim3(HID / 64, GATES / 64), dim3(256), 0, stream>>>(
      W_ih, OUTD, WoTT, OUTD, Wg2 + HID, KDIM, (const float*)nullptr, OUTD);

  // recurrence: one fused kernel per step
  unsigned short* Ap[2] = {A0, A1};
  for (int t = 0; t < SEQ; ++t) {
    k_step2<<<dim3(256), dim3(512), 0, stream>>>(
        Ap[t & 1], Ap[(t + 1) & 1], cbuf, Wg2,
        (t == 0) ? bias0 : bias2, hs, cs, t);
  }

  // outs = cs @ W_out^T + b_out  (M = 65536, N = 512, K = 1024)
  k_gemm<float, float, float>
      <<<dim3(OUTD / 64, BATCH * SEQ / 64), dim3(256), 0, stream>>>(
      cs, HID, W_out, HID, os, OUTD, b_out, HID);
}

// Round 7
// 4592.570 us; speedup vs baseline: 5.3850x; 1.0469x over previous
//
#include <hip/hip_runtime.h>
#include <cstdint>
#include <cstddef>
#include <type_traits>

// LSTM decoder: SEQ=256 steps, BATCH=256, HID=1024, OUT=512. f32 in/out.
// Folded recurrence (Wc2 = W_ih @ W_out): each step is ONE GEMM
//   gates = [h | c] @ [W_hh | Wc2]^T  (M=256, N=4096, K=2048, bf16 MFMA)
// Round-7: round-6's 8-phase counted-vmcnt pipeline with the two races fixed:
//   (a) full vmcnt(0) drain after the prologue (robust to compiler load
//       reordering: in-loop FIFO then contains ONLY our STAGE ops);
//   (b) last phase waits vmcnt(0), not vmcnt(4) (chunk 7 was unguarded).
// Chunks: 8 x (64 rows x 256 k = 32KB), triple-buffered, staged 2 ahead.
// Weights in registers (32 bf16x8). Scratch in `outs` third of d_out.

#define SEQ    256
#define BATCH  256
#define HID    1024
#define OUTD   512
#define KDIM   2048
#define GATES  4096

typedef __bf16 bf16x8 __attribute__((ext_vector_type(8)));
typedef float  f32x4  __attribute__((ext_vector_type(4)));

__device__ __forceinline__ unsigned short f2bf(float x) {
  unsigned u = __float_as_uint(x);
  u = (u + 0x7FFFu + ((u >> 16) & 1u)) >> 16;   // RNE
  return (unsigned short)u;
}

__device__ __forceinline__ f32x4 mfma16(bf16x8 a, bf16x8 b, f32x4 c) {
  return __builtin_amdgcn_mfma_f32_16x16x32_bf16(a, b, c, 0, 0, 0);
}

__device__ __forceinline__ bf16x8 ld_frag_bf(const unsigned short* p) {
  uint4 u = *reinterpret_cast<const uint4*>(p);
  return __builtin_bit_cast(bf16x8, u);
}

#define GLOAD_LDS16(gp, lp)                                                   \
  __builtin_amdgcn_global_load_lds(                                           \
      (const __attribute__((address_space(1))) unsigned int*)(gp),            \
      (__attribute__((address_space(3))) unsigned int*)(lp), 16, 0, 0)

// ---------------- prep kernels ----------------

__global__ void k_cast_whh(const float* __restrict__ whh, unsigned short* __restrict__ wg2) {
  int i4 = blockIdx.x * blockDim.x + threadIdx.x;
  if (i4 >= (GATES * HID) / 4) return;
  int idx = i4 * 4;
  int n = idx >> 10, k = idx & 1023;
  const float4 v = *reinterpret_cast<const float4*>(whh + idx);
  ushort4 o; o.x = f2bf(v.x); o.y = f2bf(v.y); o.z = f2bf(v.z); o.w = f2bf(v.w);
  *reinterpret_cast<ushort4*>(wg2 + (size_t)n * KDIM + k) = o;
}

__global__ void k_cast_wout(const float* __restrict__ wout,
                            unsigned short* __restrict__ wott) {
  int idx = blockIdx.x * blockDim.x + threadIdx.x;
  if (idx >= OUTD * HID) return;
  int j = idx >> 10, k = idx & 1023;
  wott[(size_t)k * OUTD + j] = f2bf(wout[idx]);
}

// A0 = [bf16(c_vector) | 0]; cbuf = c_vector (f32 master cell state)
__global__ void k_init(const float* __restrict__ cvec,
                       unsigned short* __restrict__ a0, float* __restrict__ cbuf) {
  int idx = blockIdx.x * blockDim.x + threadIdx.x;
  if (idx >= BATCH * KDIM) return;
  int b = idx >> 11, k = idx & 2047;
  if (k < HID) {
    float v = cvec[(size_t)b * HID + k];
    a0[idx] = f2bf(v);
    cbuf[(size_t)b * HID + k] = v;
  } else {
    a0[idx] = 0;
  }
}

// bias0[n] = b_ih+b_hh ; bias2[n] = bias0[n] + dot(W_ih[n,:], b_out)
__global__ void k_bias(const float* __restrict__ wih, const float* __restrict__ b_ih,
                       const float* __restrict__ b_hh, const float* __restrict__ b_out,
                       float* __restrict__ bias0, float* __restrict__ bias2) {
  int wave = threadIdx.x >> 6, l = threadIdx.x & 63;
  int n = blockIdx.x * 4 + wave;
  float s = 0.f;
  for (int j = l; j < OUTD; j += 64) s += wih[(size_t)n * OUTD + j] * b_out[j];
  for (int off = 32; off; off >>= 1) s += __shfl_down(s, off);
  if (l == 0) {
    float b0 = b_ih[n] + b_hh[n];
    bias0[n] = b0;
    bias2[n] = b0 + s;
  }
}

// ---------------- generic bf16-MFMA GEMM (unchanged, passing) ----------
template <typename AT>
__device__ __forceinline__ bf16x8 ld_frag(const AT* p) {
  if constexpr (std::is_same_v<AT, float>) {
    const float4 f0 = *reinterpret_cast<const float4*>(p);
    const float4 f1 = *reinterpret_cast<const float4*>(p + 4);
    uint4 v;
    v.x = (unsigned)f2bf(f0.x) | ((unsigned)f2bf(f0.y) << 16);
    v.y = (unsigned)f2bf(f0.z) | ((unsigned)f2bf(f0.w) << 16);
    v.z = (unsigned)f2bf(f1.x) | ((unsigned)f2bf(f1.y) << 16);
    v.w = (unsigned)f2bf(f1.z) | ((unsigned)f2bf(f1.w) << 16);
    return __builtin_bit_cast(bf16x8, v);
  } else {
    return ld_frag_bf(p);
  }
}

template <typename AT, typename BT, typename DT>
__global__ __launch_bounds__(256)
void k_gemm(const AT* __restrict__ A, int lda,
            const BT* __restrict__ Bn, int ldb,
            DT* __restrict__ D, int ldd,
            const float* __restrict__ bias, int K) {
  __shared__ char lds[64 * 1024];
  const int tid = threadIdx.x;
  const int w = tid >> 6, l = tid & 63;
  const int n0 = blockIdx.x * 64;
  const int m0 = blockIdx.y * 64 + w * 16;
  const int lr = l & 15, lg = l >> 4;

  f32x4 acc[4] = {};
  for (int kc = 0; kc < K; kc += 512) {
    __syncthreads();
    for (int it = 0; it < 16; ++it) {
      int idx = tid + it * 256;
      int col = idx >> 6, k16 = idx & 63;
      uint4 v;
      if constexpr (std::is_same_v<BT, float>) {
        const float* src = Bn + (size_t)(n0 + col) * ldb + kc + k16 * 8;
        const float4 f0 = *reinterpret_cast<const float4*>(src);
        const float4 f1 = *reinterpret_cast<const float4*>(src + 4);
        v.x = (unsigned)f2bf(f0.x) | ((unsigned)f2bf(f0.y) << 16);
        v.y = (unsigned)f2bf(f0.z) | ((unsigned)f2bf(f0.w) << 16);
        v.z = (unsigned)f2bf(f1.x) | ((unsigned)f2bf(f1.y) << 16);
        v.w = (unsigned)f2bf(f1.z) | ((unsigned)f2bf(f1.w) << 16);
      } else {
        v = *reinterpret_cast<const uint4*>(Bn + (size_t)(n0 + col) * ldb + kc + k16 * 8);
      }
      int db = col * 1024 + ((k16 * 16) ^ ((col & 7) << 4));
      *reinterpret_cast<uint4*>(lds + db) = v;
    }
    __syncthreads();
    const AT* Arow = A + (size_t)(m0 + lr) * lda + kc + lg * 8;
#pragma unroll
    for (int ks = 0; ks < 16; ++ks) {
      bf16x8 af = ld_frag(Arow + ks * 32);
      int kb = ks * 64 + lg * 16;
#pragma unroll
      for (int f = 0; f < 4; ++f) {
        int col = f * 16 + lr;
        uint4 u = *reinterpret_cast<const uint4*>(lds + col * 1024 + (kb ^ ((col & 7) << 4)));
        acc[f] = mfma16(af, __builtin_bit_cast(bf16x8, u), acc[f]);
      }
    }
  }
#pragma unroll
  for (int f = 0; f < 4; ++f) {
    int cg = n0 + f * 16 + lr;
    float bv = bias ? bias[cg] : 0.f;
#pragma unroll
    for (int j = 0; j < 4; ++j) {
      int r = m0 + lg * 4 + j;
      float val = acc[f][j] + bv;
      if constexpr (std::is_same_v<DT, unsigned short>) D[(size_t)r * ldd + cg] = f2bf(val);
      else                                              D[(size_t)r * ldd + cg] = val;
    }
  }
}

// ---------------- per-step fused LSTM kernel (8-phase counted-vmcnt) ------
// WG (mg,ng): mg = bid>>6 (64 batch rows), ng = bid&63 (16 hid cols = 64 gate
// rows). Waves: wn = wave>>2 (32 gate-cols), wk = wave&3 (k-split 4).
// B-frags in registers (32 x bf16x8). A staged in 8 chunks of 64 rows x 256 k
// (32 KB), triple-buffered, issued 2 chunks ahead.
// Wait discipline (per-wave FIFO contains ONLY stage ops after the prologue
// drain): phases 0-1 none; 2-6 vmcnt(4) (= chunk c ready, c+1 in flight);
// 7 vmcnt(0) (last chunk, nothing to keep in flight).
__global__ __launch_bounds__(512, 2)
void k_step3(const unsigned short* __restrict__ Acur,
             unsigned short* __restrict__ Anxt,
             float* __restrict__ cbuf,
             const unsigned short* __restrict__ Wg2,
             const float* __restrict__ bias,
             float* __restrict__ hs,
             float* __restrict__ cs,
             int t) {
  __shared__ char lds[98304];                       // 3 x 32KB chunk buffers
  const int tid = threadIdx.x;
  const int wave = tid >> 6, l = tid & 63;
  const int wn = wave >> 2, wk = wave & 3;
  const int mg = blockIdx.x >> 6, ng = blockIdx.x & 63;
  const int lr = l & 15, lg = l >> 4;

  // ---- per-thread loads (complete under the prologue drain) ----
  const int m = tid >> 3;                           // batch row in WG
  const int hcp = tid & 7;
  const int b_row = mg * 64 + m;
  const int hid0 = ng * 16 + hcp * 2;
  const float2 cold = *reinterpret_cast<const float2*>(cbuf + (size_t)b_row * HID + hid0);
  float biasr[2][4];
#pragma unroll
  for (int e = 0; e < 2; ++e)
#pragma unroll
    for (int g = 0; g < 4; ++g) biasr[e][g] = bias[g * HID + hid0 + e];

  // stage chunk c of A (64 rows x 256 k bf16 = 32KB) into LDS buffer `buf`.
  // LDS linear (global_load_lds), source-side XOR swizzle slot^(row&7).
  auto STAGE = [&](int buf, int c) {
    const unsigned short* base = Acur + (size_t)(mg * 64) * KDIM + c * 256;
#pragma unroll
    for (int it = 0; it < 4; ++it) {
      int s_lin = it * 512 + tid;
      int row = s_lin >> 5, slot = s_lin & 31;
      const unsigned short* g = base + (size_t)row * KDIM + ((slot ^ (row & 7)) * 8);
      GLOAD_LDS16(g, lds + buf * 32768 + s_lin * 16);
    }
  };

  STAGE(0, 0);
  STAGE(1, 1);

  // ---- weight fragments -> registers (32 frags = 128 VGPR) ----
  bf16x8 B[8][2][2];   // [chunk][ks][in]
#pragma unroll
  for (int c = 0; c < 8; ++c)
#pragma unroll
    for (int ks = 0; ks < 2; ++ks)
#pragma unroll
      for (int in = 0; in < 2; ++in) {
        int col = wn * 32 + in * 16 + lr;                  // WG gate-col 0..63
        int grow = (col >> 4) * HID + ng * 16 + (col & 15);
        int kb = c * 256 + wk * 64 + ks * 32 + lg * 8;
        B[c][ks][in] = ld_frag_bf(Wg2 + (size_t)grow * KDIM + kb);
      }

  // ---- prologue drain: retire EVERYTHING issued so far (early loads,
  // stage0, stage1, B) regardless of compiler issue order. After this the
  // per-wave vmcnt FIFO contains only our in-loop STAGE ops.
  asm volatile("s_waitcnt vmcnt(0)" ::: "memory");

  f32x4 acc[4][2] = {};
#pragma unroll
  for (int c = 0; c < 8; ++c) {
    if (c >= 2) {
      if (c < 7) { asm volatile("s_waitcnt vmcnt(4)" ::: "memory"); }
      else       { asm volatile("s_waitcnt vmcnt(0)" ::: "memory"); }
    }
    __builtin_amdgcn_s_barrier();
    const char* buf = lds + (c % 3) * 32768;
#pragma unroll
    for (int ks = 0; ks < 2; ++ks) {
      bf16x8 a[4];
#pragma unroll
      for (int im = 0; im < 4; ++im) {
        int row = im * 16 + lr;
        int k16 = wk * 8 + ks * 4 + lg;               // 16B slot in chunk row
        a[im] = *reinterpret_cast<const bf16x8*>(
            buf + row * 512 + ((k16 ^ (row & 7)) << 4));
      }
#pragma unroll
      for (int im = 0; im < 4; ++im)
#pragma unroll
        for (int in = 0; in < 2; ++in)
          acc[im][in] = mfma16(a[im], B[c][ks][in], acc[im][in]);
    }
    if (c <= 5) STAGE((c + 2) % 3, c + 2);
  }

  // ---- all phase-7 reads done -> dump partials into buffers 0+1 (64KB) ----
  asm volatile("" ::: "memory");
  __builtin_amdgcn_s_barrier();
#pragma unroll
  for (int im = 0; im < 4; ++im)
#pragma unroll
    for (int in = 0; in < 2; ++in)
      *reinterpret_cast<f32x4*>(lds + wave * 8192 + (im * 2 + in) * 1024 + l * 16) =
          acc[im][in];
  __syncthreads();

  // ---- epilogue: 2 consecutive cells/thread, 4-way k-reduce from LDS ----
  float cn2[2], hn2[2];
#pragma unroll
  for (int e = 0; e < 2; ++e) {
    int hc = hcp * 2 + e;
    float pre[4];
#pragma unroll
    for (int g = 0; g < 4; ++g) {
      int n = g * 16 + hc;                                 // WG gate-col
      int wn_r = n >> 5, nn = n & 31;
      int frag = ((m >> 4) << 1) | (nn >> 4);
      int lane_r = ((m & 15) >> 2) * 16 + (nn & 15);
      int j = m & 3;
      float s = 0.f;
#pragma unroll
      for (int wkk = 0; wkk < 4; ++wkk)
        s += *reinterpret_cast<const float*>(
            lds + (wn_r * 4 + wkk) * 8192 + frag * 1024 + lane_r * 16 + j * 4);
      pre[g] = s + biasr[e][g];
    }
    float si = 1.f / (1.f + __expf(-pre[0]));
    float sf = 1.f / (1.f + __expf(-pre[1]));
    float tg = tanhf(pre[2]);
    float so = 1.f / (1.f + __expf(-pre[3]));
    float co = (e == 0) ? cold.x : cold.y;
    float cn = sf * co + si * tg;
    float hn = so * tanhf(cn);
    cn2[e] = cn;
    hn2[e] = hn;
  }
  *reinterpret_cast<float2*>(cbuf + (size_t)b_row * HID + hid0) = make_float2(cn2[0], cn2[1]);
  unsigned hpack = (unsigned)f2bf(hn2[0]) | ((unsigned)f2bf(hn2[1]) << 16);
  unsigned cpack = (unsigned)f2bf(cn2[0]) | ((unsigned)f2bf(cn2[1]) << 16);
  *reinterpret_cast<unsigned*>(Anxt + (size_t)b_row * KDIM + hid0) = hpack;
  *reinterpret_cast<unsigned*>(Anxt + (size_t)b_row * KDIM + HID + hid0) = cpack;
  size_t o = (size_t)b_row * (SEQ * HID) + (size_t)t * HID + hid0;
  *reinterpret_cast<float2*>(hs + o) = make_float2(hn2[0], hn2[1]);
  *reinterpret_cast<float2*>(cs + o) = make_float2(cn2[0], cn2[1]);
}

// ---------------- launch ----------------
extern "C" void kernel_launch(void* const* d_in, const int* in_sizes, int n_in,
                              void* d_out, int out_size, void* d_ws, size_t ws_size,
                              hipStream_t stream) {
  const float* c_vec = (const float*)d_in[0];
  const float* W_ih  = (const float*)d_in[1];
  const float* W_hh  = (const float*)d_in[2];
  const float* b_ih  = (const float*)d_in[3];
  const float* b_hh  = (const float*)d_in[4];
  const float* W_out = (const float*)d_in[5];
  const float* b_out = (const float*)d_in[6];

  float* out = (float*)d_out;
  float* hs = out;
  float* cs = out + (size_t)BATCH * SEQ * HID;
  float* os = out + (size_t)2 * BATCH * SEQ * HID;

  // Scratch in the `outs` region (128 MB; final GEMM reads nothing from it).
  char* sc = (char*)os;
  unsigned short* Wg2   = (unsigned short*)(sc);                 // 16 MB
  unsigned short* WoTT  = (unsigned short*)(sc + (16u << 20));   // 1 MB
  unsigned short* A0    = (unsigned short*)(sc + (17u << 20));   // 1 MB
  unsigned short* A1    = (unsigned short*)(sc + (18u << 20));   // 1 MB
  float*          cbuf  = (float*)(sc + (19u << 20));            // 1 MB
  float*          bias0 = (float*)(sc + (20u << 20));
  float*          bias2 = (float*)(sc + (20u << 20) + 16384);

  k_cast_whh<<<dim3(GATES * HID / 4 / 256), dim3(256), 0, stream>>>(W_hh, Wg2);
  k_cast_wout<<<dim3(OUTD * HID / 256), dim3(256), 0, stream>>>(W_out, WoTT);
  k_init<<<dim3(BATCH * KDIM / 256), dim3(256), 0, stream>>>(c_vec, A0, cbuf);
  k_bias<<<dim3(GATES / 4), dim3(256), 0, stream>>>(W_ih, b_ih, b_hh, b_out, bias0, bias2);
  // Wc2 = W_ih @ W_out -> Wg2[:, 1024:2048]
  k_gemm<float, unsigned short, unsigned short>
      <<<dim3(HID / 64, GATES / 64), dim3(256), 0, stream>>>(
      W_ih, OUTD, WoTT, OUTD, Wg2 + HID, KDIM, (const float*)nullptr, OUTD);

  // recurrence: one fused kernel per step
  unsigned short* Ap[2] = {A0, A1};
  for (int t = 0; t < SEQ; ++t) {
    k_step3<<<dim3(256), dim3(512), 0, stream>>>(
        Ap[t & 1], Ap[(t + 1) & 1], cbuf, Wg2,
        (t == 0) ? bias0 : bias2, hs, cs, t);
  }

  // outs = cs @ W_out^T + b_out  (M = 65536, N = 512, K = 1024)
  k_gemm<float, float, float>
      <<<dim3(OUTD / 64, BATCH * SEQ / 64), dim3(256), 0, stream>>>(
      cs, HID, W_out, HID, os, OUTD, b_out, HID);
}